// Round 1
// baseline (220.861 us; speedup 1.0000x reference)
//
#include <hip/hip_runtime.h>
#include <math.h>

#define NB   16
#define KL   50
#define NG   76
#define NA   3
#define NCLS 80
#define NCH  85
#define CELLS (NA*NG*NG)   // 17328 per batch
#define EPSF 1e-7f

__device__ __forceinline__ float sigmoidf(float x) {
    return 1.0f / (1.0f + expf(-x));
}

__device__ __forceinline__ float bcef(float p, float t) {
    p = fminf(fmaxf(p, EPSF), 1.0f - EPSF);
    return -(t * logf(p) + (1.0f - t) * logf(1.0f - p));
}

// One block per batch, 64 threads (one wave). Thread k handles label k.
__global__ __launch_bounds__(64) void yolo_prep(
    const float* __restrict__ labels,       // [NB, KL, 5]
    const float* __restrict__ anchors_all,  // [9, 2]
    const int*   __restrict__ anchor_indices, // [3]
    const int*   __restrict__ img_size_p,
    int*   __restrict__ lab_idx,            // [NB*CELLS], -1 = no obj
    float* __restrict__ gt_ws,              // [NB*KL*4]
    float* __restrict__ tgt_ws,             // [NB*KL*4]
    float* __restrict__ ts_ws,              // [NB*KL]
    int*   __restrict__ tc_ws,              // [NB*KL]
    float* __restrict__ out)
{
    const int b = blockIdx.x;
    const int k = threadIdx.x;
    const float img = (float)img_size_p[0];

    __shared__ int s_valid[KL], s_bn[KL], s_ti[KL], s_tj[KL];

    // init this batch's lab_idx slice (ws is poisoned 0xAA every call)
    int* slice = lab_idx + b * CELLS;
    for (int idx = k; idx < CELLS; idx += 64) slice[idx] = -1;

    int has = 0;
    float cls = 0.f, tx = 0.f, ty = 0.f, tw = 0.f, th = 0.f;
    if (k < KL) {
        const float* L = labels + ((size_t)b * KL + k) * 5;
        cls = L[0];
        float lx = L[1], ly = L[2];
        tw = L[3]; th = L[4];
        has = ((cls + lx + ly + tw + th) > 0.0f) ? 1 : 0;
        tx = lx * (float)NG;
        ty = ly * (float)NG;
    }
    unsigned long long bal = __ballot(has);
    int nlabel = __popcll(bal);

    if (k < KL) {
        int valid_k = (k < nlabel) ? 1 : 0;

        // IoU of (0,0,tw,th) vs (0,0,aw/img,ah/img) for all 9 anchors; argmax (first max wins)
        float best = -1.0f; int bestn = 0;
        float area_t = tw * th;
        for (int n = 0; n < 9; ++n) {
            float aw = anchors_all[n * 2 + 0] / img;
            float ah = anchors_all[n * 2 + 1] / img;
            float iw = fminf(tw * 0.5f, aw * 0.5f) - fmaxf(-tw * 0.5f, -aw * 0.5f);
            float ih = fminf(th * 0.5f, ah * 0.5f) - fmaxf(-th * 0.5f, -ah * 0.5f);
            iw = fmaxf(iw, 0.0f); ih = fmaxf(ih, 0.0f);
            float inter = iw * ih;
            float iou = inter / fmaxf(area_t + aw * ah - inter, 1e-16f);
            if (iou > best) { best = iou; bestn = n; }
        }
        int va = 0;
        for (int t = 0; t < 3; ++t) va |= (bestn == anchor_indices[t]) ? 1 : 0;
        int valid = (valid_k && va) ? 1 : 0;
        int bn = bestn % NA;
        int ti = (int)tx, tj = (int)ty;

        float vkf = valid_k ? 1.0f : 0.0f;
        float* G = gt_ws + ((size_t)b * KL + k) * 4;
        G[0] = (tx / (float)NG) * vkf;
        G[1] = (ty / (float)NG) * vkf;
        G[2] = tw * vkf;
        G[3] = th * vkf;

        float naw = anchors_all[anchor_indices[bn] * 2 + 0] / img;
        float nah = anchors_all[anchor_indices[bn] * 2 + 1] / img;
        float* T = tgt_ws + ((size_t)b * KL + k) * 4;
        T[0] = tx - floorf(tx);
        T[1] = ty - floorf(ty);
        T[2] = logf(tw / naw + 1e-16f);
        T[3] = logf(th / nah + 1e-16f);
        ts_ws[b * KL + k] = sqrtf(2.0f - tw * th);
        tc_ws[b * KL + k] = (int)cls;

        // mode='drop' semantics
        if (ti < 0 || ti >= NG || tj < 0 || tj >= NG) valid = 0;
        s_valid[k] = valid; s_bn[k] = bn; s_ti[k] = ti; s_tj[k] = tj;
    }
    __syncthreads();

    // sequential scatter: last k wins (matches in-order duplicate .set)
    if (k == 0) {
        for (int kk = 0; kk < KL; ++kk) {
            if (s_valid[kk]) {
                slice[s_bn[kk] * NG * NG + s_tj[kk] * NG + s_ti[kk]] = kk;
            }
        }
        if (b == 0) out[0] = 0.0f;
    }
}

// grid: (ceil(CELLS/256), NB), block 256
__global__ __launch_bounds__(256) void yolo_loss(
    const float* __restrict__ raw,          // [NB, NA*NCH, NG, NG]
    const float* __restrict__ anchors_all,
    const int*   __restrict__ anchor_indices,
    const int*   __restrict__ img_size_p,
    const int*   __restrict__ lab_idx,
    const float* __restrict__ gt_ws,
    const float* __restrict__ tgt_ws,
    const float* __restrict__ ts_ws,
    const int*   __restrict__ tc_ws,
    float* __restrict__ out)
{
    const int b = blockIdx.y;
    const int c = blockIdx.x * blockDim.x + threadIdx.x;

    __shared__ float s_gt[KL * 4];
    __shared__ float s_tgt[KL * 4];
    __shared__ float s_ts[KL];
    __shared__ int   s_tc[KL];
    for (int idx = threadIdx.x; idx < KL * 4; idx += blockDim.x) {
        s_gt[idx]  = gt_ws[(size_t)b * KL * 4 + idx];
        s_tgt[idx] = tgt_ws[(size_t)b * KL * 4 + idx];
    }
    for (int idx = threadIdx.x; idx < KL; idx += blockDim.x) {
        s_ts[idx] = ts_ws[b * KL + idx];
        s_tc[idx] = tc_ws[b * KL + idx];
    }
    __syncthreads();

    float loss = 0.0f;
    if (c < CELLS) {
        const int a = c / (NG * NG);
        const int r = c % (NG * NG);
        const int j = r / NG;
        const int i = r % NG;
        const float img = (float)img_size_p[0];
        const int CS = NG * NG;
        const float* R = raw + ((size_t)b * NA * NCH + (size_t)a * NCH) * CS
                             + (size_t)j * NG + i;

        float rx = R[0 * CS], ry = R[1 * CS];
        float rw = R[2 * CS], rh = R[3 * CS];
        float rc = R[4 * CS];

        float sx = sigmoidf(rx), sy = sigmoidf(ry);
        float sconf = sigmoidf(rc);

        int ai = anchor_indices[a];
        float aw = anchors_all[ai * 2 + 0] / img;
        float ah = anchors_all[ai * 2 + 1] / img;

        float px = (sx + (float)i) / (float)NG;
        float py = (sy + (float)j) / (float)NG;
        float pw = fminf(expf(rw) * aw, 1.0f);
        float ph = fminf(expf(rh) * ah, 1.0f);

        float areaA = pw * ph;
        float ax0 = px - pw * 0.5f, ax1 = px + pw * 0.5f;
        float ay0 = py - ph * 0.5f, ay1 = py + ph * 0.5f;

        float maxiou = 0.0f;
        #pragma unroll 5
        for (int k = 0; k < KL; ++k) {
            float gx = s_gt[k * 4 + 0], gy = s_gt[k * 4 + 1];
            float gw = s_gt[k * 4 + 2], gh = s_gt[k * 4 + 3];
            float tlx = fmaxf(ax0, gx - gw * 0.5f);
            float tly = fmaxf(ay0, gy - gh * 0.5f);
            float brx = fminf(ax1, gx + gw * 0.5f);
            float bry = fminf(ay1, gy + gh * 0.5f);
            float iw = fmaxf(brx - tlx, 0.0f);
            float ih = fmaxf(bry - tly, 0.0f);
            float inter = iw * ih;
            float iou = inter / fmaxf(areaA + gw * gh - inter, 1e-16f);
            maxiou = fmaxf(maxiou, iou);
        }
        bool ignore = maxiou > 0.6f;
        int kobj = lab_idx[(size_t)b * CELLS + c];
        bool obj = kobj >= 0;
        bool pen = (!ignore) || obj;

        if (pen) loss += bcef(sconf, obj ? 1.0f : 0.0f);
        if (obj) {
            float ts = s_ts[kobj];
            float w2 = ts * ts;
            loss += w2 * (bcef(sx, s_tgt[kobj * 4 + 0]) + bcef(sy, s_tgt[kobj * 4 + 1]));
            float dw = rw - s_tgt[kobj * 4 + 2];
            float dh = rh - s_tgt[kobj * 4 + 3];
            loss += 0.5f * w2 * (dw * dw + dh * dh);
            int tc = s_tc[kobj];
            for (int cc = 0; cc < NCLS; ++cc) {
                float p = sigmoidf(R[(5 + cc) * CS]);
                loss += bcef(p, (cc == tc) ? 1.0f : 0.0f);
            }
        }
    }

    // wave-64 reduction, one atomic per wave
    for (int off = 32; off > 0; off >>= 1)
        loss += __shfl_down(loss, off, 64);
    if ((threadIdx.x & 63) == 0 && loss != 0.0f)
        atomicAdd(out, loss);
}

extern "C" void kernel_launch(void* const* d_in, const int* in_sizes, int n_in,
                              void* d_out, int out_size, void* d_ws, size_t ws_size,
                              hipStream_t stream) {
    const float* raw            = (const float*)d_in[0];
    const float* labels         = (const float*)d_in[1];
    const float* anchors_all    = (const float*)d_in[2];
    const int*   anchor_indices = (const int*)d_in[3];
    const int*   img_size_p     = (const int*)d_in[4];
    float* out = (float*)d_out;

    // workspace carve-up
    char* ws = (char*)d_ws;
    int*   lab_idx = (int*)ws;                      ws += sizeof(int)   * NB * CELLS;
    float* gt_ws   = (float*)ws;                    ws += sizeof(float) * NB * KL * 4;
    float* tgt_ws  = (float*)ws;                    ws += sizeof(float) * NB * KL * 4;
    float* ts_ws   = (float*)ws;                    ws += sizeof(float) * NB * KL;
    int*   tc_ws   = (int*)ws;                      ws += sizeof(int)   * NB * KL;

    yolo_prep<<<NB, 64, 0, stream>>>(labels, anchors_all, anchor_indices, img_size_p,
                                     lab_idx, gt_ws, tgt_ws, ts_ws, tc_ws, out);

    dim3 grid((CELLS + 255) / 256, NB);
    yolo_loss<<<grid, 256, 0, stream>>>(raw, anchors_all, anchor_indices, img_size_p,
                                        lab_idx, gt_ws, tgt_ws, ts_ws, tc_ws, out);
}

// Round 2
// 147.836 us; speedup vs baseline: 1.4940x; 1.4940x over previous
//
#include <hip/hip_runtime.h>
#include <math.h>

#define NB   16
#define KL   50
#define NG   76
#define NA   3
#define NCLS 80
#define NCH  85
#define GG   (NG*NG)            // 5776
#define CELLS (NA*GG)           // 17328
#define LOSS_BX ((CELLS + 255) / 256)   // 68
#define NPART (LOSS_BX * NB)            // 1088

__device__ __forceinline__ float softplusf(float x) {
    // log(1 + exp(x)), stable for all x; __expf/__logf are native v_exp/v_log
    float t = __expf(-fabsf(x));
    return fmaxf(x, 0.0f) + __logf(1.0f + t);
}

// 16 blocks x 64 threads: per-label decode. No big scatter array anymore.
__global__ __launch_bounds__(64) void yolo_prep(
    const float* __restrict__ labels,        // [NB, KL, 5]
    const float* __restrict__ anchors_all,   // [9, 2]
    const int*   __restrict__ anchor_indices,// [3]
    const int*   __restrict__ img_size_p,
    int*    __restrict__ meta_ws,   // [NB*KL]  cell index (a*GG+tj*NG+ti) or -1
    float4* __restrict__ box_ws,    // [NB*KL]  GT box corners x0,y0,x1,y1
    float*  __restrict__ c_ws,      // [NB*KL]  0.375 * areaB
    float*  __restrict__ tgt_ws,    // [NB*KL*4]
    float*  __restrict__ w2_ws,     // [NB*KL]  (2 - tw*th)
    int*    __restrict__ tc_ws)     // [NB*KL]
{
    const int b = blockIdx.x;
    const int k = threadIdx.x;
    const float img = (float)img_size_p[0];

    int has = 0;
    float cls = 0.f, tx = 0.f, ty = 0.f, tw = 0.f, th = 0.f;
    if (k < KL) {
        const float* L = labels + ((size_t)b * KL + k) * 5;
        cls = L[0];
        float lx = L[1], ly = L[2];
        tw = L[3]; th = L[4];
        has = ((cls + lx + ly + tw + th) > 0.0f) ? 1 : 0;
        tx = lx * (float)NG;
        ty = ly * (float)NG;
    }
    unsigned long long bal = __ballot(has);
    int nlabel = __popcll(bal);
    if (k >= KL) return;

    int valid_k = (k < nlabel) ? 1 : 0;

    // anchor argmax: both boxes centered at origin -> overlap = min(w)*min(h).
    // Keep the exact division here (runs 9x per label only; argmax is
    // selection-sensitive so don't approximate).
    float best = -1.0f; int bestn = 0;
    float area_t = tw * th;
    for (int n = 0; n < 9; ++n) {
        float aw = anchors_all[2 * n + 0] / img;
        float ah = anchors_all[2 * n + 1] / img;
        float inter = fmaxf(fminf(tw, aw), 0.0f) * fmaxf(fminf(th, ah), 0.0f);
        float iou = inter / fmaxf(area_t + aw * ah - inter, 1e-16f);
        if (iou > best) { best = iou; bestn = n; }   // first max wins (jnp.argmax)
    }
    int va = 0;
    for (int t = 0; t < 3; ++t) va |= (bestn == anchor_indices[t]) ? 1 : 0;
    int bn = bestn % NA;
    int ti = (int)tx, tj = (int)ty;
    int valid = valid_k && va && (ti >= 0) && (ti < NG) && (tj >= 0) && (tj < NG);

    const size_t idx = (size_t)b * KL + k;
    meta_ws[idx] = valid ? (bn * GG + tj * NG + ti) : -1;

    float vkf = valid_k ? 1.0f : 0.0f;
    float gx = (tx / (float)NG) * vkf;
    float gy = (ty / (float)NG) * vkf;
    float gw = tw * vkf;
    float gh = th * vkf;
    box_ws[idx] = make_float4(gx - 0.5f * gw, gy - 0.5f * gh,
                              gx + 0.5f * gw, gy + 0.5f * gh);
    c_ws[idx] = 0.375f * (gw * gh);   // 0.6/1.6 * areaB

    float naw = anchors_all[anchor_indices[bn] * 2 + 0] / img;
    float nah = anchors_all[anchor_indices[bn] * 2 + 1] / img;
    float* T = tgt_ws + idx * 4;
    T[0] = tx - floorf(tx);
    T[1] = ty - floorf(ty);
    T[2] = logf(tw / naw + 1e-16f);
    T[3] = logf(th / nah + 1e-16f);
    w2_ws[idx] = 2.0f - tw * th;      // == tgt_scale^2 up to 1 ulp
    tc_ws[idx] = (int)cls;
}

// grid (68, 16) x 256: per-cell loss, division-free ignore test,
// obj lookup fused into the K-loop, block-reduced partials (no atomics).
__global__ __launch_bounds__(256) void yolo_loss(
    const float* __restrict__ raw,
    const float* __restrict__ anchors_all,
    const int*   __restrict__ anchor_indices,
    const int*   __restrict__ img_size_p,
    const int*   __restrict__ meta_ws,
    const float4* __restrict__ box_ws,
    const float* __restrict__ c_ws,
    const float* __restrict__ tgt_ws,
    const float* __restrict__ w2_ws,
    const int*   __restrict__ tc_ws,
    float* __restrict__ partials)
{
    const int b = blockIdx.y;
    const int c = blockIdx.x * 256 + threadIdx.x;

    __shared__ float4 s_box[KL];
    __shared__ float  s_c[KL];
    __shared__ int    s_meta[KL];
    __shared__ float  s_tgt[KL * 4];
    __shared__ float  s_w2[KL];
    __shared__ int    s_tc[KL];
    __shared__ float  s_red[4];

    if (threadIdx.x < KL) {
        size_t idx = (size_t)b * KL + threadIdx.x;
        s_box[threadIdx.x]  = box_ws[idx];
        s_c[threadIdx.x]    = c_ws[idx];
        s_meta[threadIdx.x] = meta_ws[idx];
        s_w2[threadIdx.x]   = w2_ws[idx];
        s_tc[threadIdx.x]   = tc_ws[idx];
    }
    if (threadIdx.x < KL * 4)
        s_tgt[threadIdx.x] = tgt_ws[(size_t)b * KL * 4 + threadIdx.x];
    __syncthreads();

    float loss = 0.0f;
    if (c < CELLS) {
        const int a = c / GG;
        const int r = c - a * GG;
        const int j = r / NG;
        const int i = r - j * NG;
        const float img = (float)img_size_p[0];
        const float* R = raw + ((size_t)(b * NA + a) * NCH) * GG + r;

        float rx = R[0],        ry = R[GG];
        float rw = R[2 * GG],   rh = R[3 * GG];
        float rc = R[4 * GG];

        // sigmoids only needed for the pred-box center
        float sx = __builtin_amdgcn_rcpf(1.0f + __expf(-rx));
        float sy = __builtin_amdgcn_rcpf(1.0f + __expf(-ry));

        int ai = anchor_indices[a];
        float aw = anchors_all[2 * ai + 0] / img;
        float ah = anchors_all[2 * ai + 1] / img;

        float px = (sx + (float)i) * (1.0f / (float)NG);
        float py = (sy + (float)j) * (1.0f / (float)NG);
        float pw = fminf(__expf(rw) * aw, 1.0f);
        float ph = fminf(__expf(rh) * ah, 1.0f);

        float areaA = pw * ph;
        float tA = 0.375f * areaA;        // 0.6/1.6 * areaA
        float ax0 = px - 0.5f * pw, ax1 = px + 0.5f * pw;
        float ay0 = py - 0.5f * ph, ay1 = py + 0.5f * ph;

        float margin = -1.0f;
        int kobj = -1;
        #pragma unroll 10
        for (int k = 0; k < KL; ++k) {
            float4 g = s_box[k];                 // broadcast LDS read
            float iw = fminf(ax1, g.z) - fmaxf(ax0, g.x);
            float ih = fminf(ay1, g.w) - fmaxf(ay0, g.y);
            float inter = fmaxf(iw, 0.0f) * fmaxf(ih, 0.0f);
            // iou > 0.6  <=>  inter > 0.375*(areaA+areaB)
            margin = fmaxf(margin, inter - (tA + s_c[k]));
            kobj = (s_meta[k] == c) ? k : kobj;  // ascending k => last wins
        }
        bool ignore = margin > 0.0f;
        bool obj = kobj >= 0;

        // bce(sigmoid(z), t) == softplus(z) - t*z
        if (obj || !ignore)
            loss = softplusf(rc) - (obj ? rc : 0.0f);

        if (obj) {
            float w2 = s_w2[kobj];
            float t0 = s_tgt[4 * kobj + 0], t1 = s_tgt[4 * kobj + 1];
            float t2 = s_tgt[4 * kobj + 2], t3 = s_tgt[4 * kobj + 3];
            loss += w2 * ((softplusf(rx) - t0 * rx) + (softplusf(ry) - t1 * ry));
            float dw = rw - t2, dh = rh - t3;
            loss += 0.5f * w2 * (dw * dw + dh * dh);
            int tc = s_tc[kobj];
            float cl = 0.0f;
            #pragma unroll 8
            for (int cc = 0; cc < NCLS; ++cc) {
                float z = R[(5 + cc) * GG];
                cl += softplusf(z);
                if (cc == tc) cl -= z;
            }
            loss += cl;
        }
    }

    // wave-64 shuffle reduce -> 4 wave partials -> block partial (no atomics)
    for (int off = 32; off > 0; off >>= 1)
        loss += __shfl_down(loss, off, 64);
    if ((threadIdx.x & 63) == 0) s_red[threadIdx.x >> 6] = loss;
    __syncthreads();
    if (threadIdx.x == 0)
        partials[(size_t)blockIdx.y * gridDim.x + blockIdx.x] =
            s_red[0] + s_red[1] + s_red[2] + s_red[3];
}

__global__ __launch_bounds__(256) void yolo_finalize(
    const float* __restrict__ partials, float* __restrict__ out)
{
    float s = 0.0f;
    for (int i = threadIdx.x; i < NPART; i += 256) s += partials[i];
    for (int off = 32; off > 0; off >>= 1)
        s += __shfl_down(s, off, 64);
    __shared__ float red[4];
    if ((threadIdx.x & 63) == 0) red[threadIdx.x >> 6] = s;
    __syncthreads();
    if (threadIdx.x == 0) out[0] = red[0] + red[1] + red[2] + red[3];
}

extern "C" void kernel_launch(void* const* d_in, const int* in_sizes, int n_in,
                              void* d_out, int out_size, void* d_ws, size_t ws_size,
                              hipStream_t stream) {
    const float* raw            = (const float*)d_in[0];
    const float* labels         = (const float*)d_in[1];
    const float* anchors_all    = (const float*)d_in[2];
    const int*   anchor_indices = (const int*)d_in[3];
    const int*   img_size_p     = (const int*)d_in[4];
    float* out = (float*)d_out;

    // workspace carve-up (d_ws is 256-aligned; keep float4 first)
    char* ws = (char*)d_ws;
    float4* box_ws  = (float4*)ws;  ws += sizeof(float4) * NB * KL;
    float*  tgt_ws  = (float*)ws;   ws += sizeof(float)  * NB * KL * 4;
    float*  c_ws    = (float*)ws;   ws += sizeof(float)  * NB * KL;
    float*  w2_ws   = (float*)ws;   ws += sizeof(float)  * NB * KL;
    int*    meta_ws = (int*)ws;     ws += sizeof(int)    * NB * KL;
    int*    tc_ws   = (int*)ws;     ws += sizeof(int)    * NB * KL;
    float*  partials= (float*)ws;   ws += sizeof(float)  * NPART;

    yolo_prep<<<NB, 64, 0, stream>>>(labels, anchors_all, anchor_indices,
                                     img_size_p, meta_ws, box_ws, c_ws,
                                     tgt_ws, w2_ws, tc_ws);

    dim3 grid(LOSS_BX, NB);
    yolo_loss<<<grid, 256, 0, stream>>>(raw, anchors_all, anchor_indices,
                                        img_size_p, meta_ws, box_ws, c_ws,
                                        tgt_ws, w2_ws, tc_ws, partials);

    yolo_finalize<<<1, 256, 0, stream>>>(partials, out);
}

// Round 3
// 146.203 us; speedup vs baseline: 1.5106x; 1.0112x over previous
//
#include <hip/hip_runtime.h>
#include <math.h>

#define NB   16
#define KL   50
#define NG   76
#define NA   3
#define NCLS 80
#define NCH  85
#define GG   (NG*NG)            // 5776
#define CELLS (NA*GG)           // 17328
#define LOSS_BX ((CELLS + 255) / 256)   // 68
#define NPART (LOSS_BX * NB)            // 1088

__device__ __forceinline__ float softplusf(float x) {
    // log(1 + exp(x)), stable for all x; __expf/__logf are native v_exp/v_log
    float t = __expf(-fabsf(x));
    return fmaxf(x, 0.0f) + __logf(1.0f + t);
}

// 16 blocks x 64 threads: per-label decode.
__global__ __launch_bounds__(64) void yolo_prep(
    const float* __restrict__ labels,        // [NB, KL, 5]
    const float* __restrict__ anchors_all,   // [9, 2]
    const int*   __restrict__ anchor_indices,// [3]
    const int*   __restrict__ img_size_p,
    int*    __restrict__ meta_ws,   // [NB*KL]  cell index (a*GG+tj*NG+ti) or -1
    float4* __restrict__ box_ws,    // [NB*KL]  GT box corners x0,y0,x1,y1
    float*  __restrict__ c_ws,      // [NB*KL]  0.375 * areaB
    float*  __restrict__ tgt_ws,    // [NB*KL*4]
    float*  __restrict__ w2_ws,     // [NB*KL]  (2 - tw*th)
    int*    __restrict__ tc_ws)     // [NB*KL]
{
    const int b = blockIdx.x;
    const int k = threadIdx.x;
    const float img = (float)img_size_p[0];

    int has = 0;
    float cls = 0.f, tx = 0.f, ty = 0.f, tw = 0.f, th = 0.f;
    if (k < KL) {
        const float* L = labels + ((size_t)b * KL + k) * 5;
        cls = L[0];
        float lx = L[1], ly = L[2];
        tw = L[3]; th = L[4];
        has = ((cls + lx + ly + tw + th) > 0.0f) ? 1 : 0;
        tx = lx * (float)NG;
        ty = ly * (float)NG;
    }
    unsigned long long bal = __ballot(has);
    int nlabel = __popcll(bal);
    if (k >= KL) return;

    int valid_k = (k < nlabel) ? 1 : 0;

    // anchor argmax: both boxes centered at origin -> overlap = min(w)*min(h).
    float best = -1.0f; int bestn = 0;
    float area_t = tw * th;
    for (int n = 0; n < 9; ++n) {
        float aw = anchors_all[2 * n + 0] / img;
        float ah = anchors_all[2 * n + 1] / img;
        float inter = fmaxf(fminf(tw, aw), 0.0f) * fmaxf(fminf(th, ah), 0.0f);
        float iou = inter / fmaxf(area_t + aw * ah - inter, 1e-16f);
        if (iou > best) { best = iou; bestn = n; }   // first max wins (jnp.argmax)
    }
    int va = 0;
    for (int t = 0; t < 3; ++t) va |= (bestn == anchor_indices[t]) ? 1 : 0;
    int bn = bestn % NA;
    int ti = (int)tx, tj = (int)ty;
    int valid = valid_k && va && (ti >= 0) && (ti < NG) && (tj >= 0) && (tj < NG);

    const size_t idx = (size_t)b * KL + k;
    meta_ws[idx] = valid ? (bn * GG + tj * NG + ti) : -1;

    float vkf = valid_k ? 1.0f : 0.0f;
    float gx = (tx / (float)NG) * vkf;
    float gy = (ty / (float)NG) * vkf;
    float gw = tw * vkf;
    float gh = th * vkf;
    box_ws[idx] = make_float4(gx - 0.5f * gw, gy - 0.5f * gh,
                              gx + 0.5f * gw, gy + 0.5f * gh);
    c_ws[idx] = 0.375f * (gw * gh);   // 0.6/1.6 * areaB

    float naw = anchors_all[anchor_indices[bn] * 2 + 0] / img;
    float nah = anchors_all[anchor_indices[bn] * 2 + 1] / img;
    float* T = tgt_ws + idx * 4;
    T[0] = tx - floorf(tx);
    T[1] = ty - floorf(ty);
    T[2] = logf(tw / naw + 1e-16f);
    T[3] = logf(th / nah + 1e-16f);
    w2_ws[idx] = 2.0f - tw * th;      // == tgt_scale^2 up to 1 ulp
    tc_ws[idx] = (int)cls;
}

// grid (68, 16) x 256. GT data read via WAVE-UNIFORM global loads -> compiler
// emits s_load into SGPRs (scalar cache): zero LDS pressure in the hot loop.
// The k-loop is kept in uniform control flow (dead lanes clamp to cell 0 and
// zero their contribution at the end) so uniformity analysis scalarizes it.
__global__ __launch_bounds__(256) void yolo_loss(
    const float* __restrict__ raw,
    const float* __restrict__ anchors_all,
    const int*   __restrict__ anchor_indices,
    const int*   __restrict__ img_size_p,
    const int*   __restrict__ meta_ws,
    const float4* __restrict__ box_ws,
    const float* __restrict__ c_ws,
    const float* __restrict__ tgt_ws,
    const float* __restrict__ w2_ws,
    const int*   __restrict__ tc_ws,
    float* __restrict__ partials)
{
    const int b = blockIdx.y;
    const int c0 = blockIdx.x * 256 + threadIdx.x;
    const bool live = c0 < CELLS;
    const int c = live ? c0 : 0;           // clamp: keep control flow uniform

    const int a = c / GG;
    const int r = c - a * GG;
    const int j = r / NG;
    const int i = r - j * NG;
    const float img = (float)img_size_p[0];
    const float* R = raw + ((size_t)(b * NA + a) * NCH) * GG + r;

    float rx = R[0],        ry = R[GG];
    float rw = R[2 * GG],   rh = R[3 * GG];
    float rc = R[4 * GG];

    float sx = __builtin_amdgcn_rcpf(1.0f + __expf(-rx));
    float sy = __builtin_amdgcn_rcpf(1.0f + __expf(-ry));

    int ai = anchor_indices[a];
    float aw = anchors_all[2 * ai + 0] / img;
    float ah = anchors_all[2 * ai + 1] / img;

    float px = (sx + (float)i) * (1.0f / (float)NG);
    float py = (sy + (float)j) * (1.0f / (float)NG);
    float pw = fminf(__expf(rw) * aw, 1.0f);
    float ph = fminf(__expf(rh) * ah, 1.0f);

    float tA = 0.375f * (pw * ph);        // 0.6/1.6 * areaA
    float ax0 = px - 0.5f * pw, ax1 = px + 0.5f * pw;
    float ay0 = py - 0.5f * ph, ay1 = py + 0.5f * ph;

    // per-batch GT arrays, indexed uniformly by k -> scalar loads
    const float4* __restrict__ Gbox  = box_ws  + (size_t)b * KL;
    const float*  __restrict__ Gc    = c_ws    + (size_t)b * KL;
    const int*    __restrict__ Gmeta = meta_ws + (size_t)b * KL;

    float margin = -1.0f;   // max_k (inter_k - 0.375*areaB_k)
    int kobj = -1;
    #pragma unroll 10
    for (int k = 0; k < KL; ++k) {
        float4 g = Gbox[k];                  // s_load_dwordx4
        float cB = Gc[k];                    // s_load_dword
        int   mk = Gmeta[k];                 // s_load_dword
        float iw = fminf(ax1, g.z) - fmaxf(ax0, g.x);
        float ih = fminf(ay1, g.w) - fmaxf(ay0, g.y);
        float inter = fmaxf(iw, 0.0f) * fmaxf(ih, 0.0f);
        margin = fmaxf(margin, inter - cB);
        kobj = (mk == c) ? k : kobj;         // ascending k => last wins
    }
    bool ignore = margin > tA;               // iou>0.6 <=> inter>0.375(areaA+areaB)
    bool obj = (kobj >= 0) && live;

    float loss = 0.0f;
    // bce(sigmoid(z), t) == softplus(z) - t*z
    if (obj || !ignore)
        loss = softplusf(rc) - (obj ? rc : 0.0f);

    if (obj) {
        size_t kb = (size_t)b * KL + kobj;
        float w2 = w2_ws[kb];
        float t0 = tgt_ws[4 * kb + 0], t1 = tgt_ws[4 * kb + 1];
        float t2 = tgt_ws[4 * kb + 2], t3 = tgt_ws[4 * kb + 3];
        loss += w2 * ((softplusf(rx) - t0 * rx) + (softplusf(ry) - t1 * ry));
        float dw = rw - t2, dh = rh - t3;
        loss += 0.5f * w2 * (dw * dw + dh * dh);
        int tc = tc_ws[kb];
        float cl = 0.0f;
        #pragma unroll 8
        for (int cc = 0; cc < NCLS; ++cc) {
            float z = R[(5 + cc) * GG];
            cl += softplusf(z);
            if (cc == tc) cl -= z;
        }
        loss += cl;
    }
    if (!live) loss = 0.0f;

    // wave-64 shuffle reduce -> 4 wave partials -> block partial (no atomics)
    for (int off = 32; off > 0; off >>= 1)
        loss += __shfl_down(loss, off, 64);
    __shared__ float s_red[4];
    if ((threadIdx.x & 63) == 0) s_red[threadIdx.x >> 6] = loss;
    __syncthreads();
    if (threadIdx.x == 0)
        partials[(size_t)blockIdx.y * gridDim.x + blockIdx.x] =
            s_red[0] + s_red[1] + s_red[2] + s_red[3];
}

__global__ __launch_bounds__(256) void yolo_finalize(
    const float* __restrict__ partials, float* __restrict__ out)
{
    float s = 0.0f;
    for (int i = threadIdx.x; i < NPART; i += 256) s += partials[i];
    for (int off = 32; off > 0; off >>= 1)
        s += __shfl_down(s, off, 64);
    __shared__ float red[4];
    if ((threadIdx.x & 63) == 0) red[threadIdx.x >> 6] = s;
    __syncthreads();
    if (threadIdx.x == 0) out[0] = red[0] + red[1] + red[2] + red[3];
}

extern "C" void kernel_launch(void* const* d_in, const int* in_sizes, int n_in,
                              void* d_out, int out_size, void* d_ws, size_t ws_size,
                              hipStream_t stream) {
    const float* raw            = (const float*)d_in[0];
    const float* labels         = (const float*)d_in[1];
    const float* anchors_all    = (const float*)d_in[2];
    const int*   anchor_indices = (const int*)d_in[3];
    const int*   img_size_p     = (const int*)d_in[4];
    float* out = (float*)d_out;

    // workspace carve-up (d_ws is 256-aligned; keep float4 first)
    char* ws = (char*)d_ws;
    float4* box_ws  = (float4*)ws;  ws += sizeof(float4) * NB * KL;
    float*  tgt_ws  = (float*)ws;   ws += sizeof(float)  * NB * KL * 4;
    float*  c_ws    = (float*)ws;   ws += sizeof(float)  * NB * KL;
    float*  w2_ws   = (float*)ws;   ws += sizeof(float)  * NB * KL;
    int*    meta_ws = (int*)ws;     ws += sizeof(int)    * NB * KL;
    int*    tc_ws   = (int*)ws;     ws += sizeof(int)    * NB * KL;
    float*  partials= (float*)ws;   ws += sizeof(float)  * NPART;

    yolo_prep<<<NB, 64, 0, stream>>>(labels, anchors_all, anchor_indices,
                                     img_size_p, meta_ws, box_ws, c_ws,
                                     tgt_ws, w2_ws, tc_ws);

    dim3 grid(LOSS_BX, NB);
    yolo_loss<<<grid, 256, 0, stream>>>(raw, anchors_all, anchor_indices,
                                        img_size_p, meta_ws, box_ws, c_ws,
                                        tgt_ws, w2_ws, tc_ws, partials);

    yolo_finalize<<<1, 256, 0, stream>>>(partials, out);
}

// Round 4
// 142.543 us; speedup vs baseline: 1.5494x; 1.0257x over previous
//
#include <hip/hip_runtime.h>
#include <math.h>

#define NB   16
#define KL   50
#define NG   76
#define NA   3
#define NCLS 80
#define NCH  85
#define GG   (NG*NG)            // 5776
#define CELLS (NA*GG)           // 17328
#define LOSS_BX ((CELLS + 255) / 256)   // 68
#define NPART (LOSS_BX * NB)            // 1088

__device__ __forceinline__ float softplusf(float x) {
    // log(1 + exp(x)), stable for all x; __expf/__logf are native v_exp/v_log
    float t = __expf(-fabsf(x));
    return fmaxf(x, 0.0f) + __logf(1.0f + t);
}

// grid (68, 16) x 256. Single fused kernel:
//   phase 1: wave 0 decodes this batch's 50 labels into LDS (redundant per
//            block — cheaper than a separate 16-wave prep kernel + graph gap)
//   phase 2: per-cell loss with division-free ignore test, obj lookup fused
//            into the K-loop (LDS broadcast reads, conflict-free)
//   phase 3: wave shfl + LDS reduce -> one partial per block (no atomics)
__global__ __launch_bounds__(256) void yolo_fused(
    const float* __restrict__ raw,           // [NB, NA*NCH, NG, NG]
    const float* __restrict__ labels,        // [NB, KL, 5]
    const float* __restrict__ anchors_all,   // [9, 2]
    const int*   __restrict__ anchor_indices,// [3]
    const int*   __restrict__ img_size_p,
    float* __restrict__ partials)            // [NPART]
{
    const int b = blockIdx.y;

    __shared__ float4 s_box[KL];     // GT corners x0,y0,x1,y1
    __shared__ float  s_c[KL];       // 0.375 * areaB
    __shared__ int    s_meta[KL];    // obj cell index or -1
    __shared__ float  s_tgt[KL][4];
    __shared__ float  s_w2[KL];
    __shared__ int    s_tc[KL];
    __shared__ float  s_red[4];

    const float img = (float)img_size_p[0];
    const float inv_img = __builtin_amdgcn_rcpf(img);

    // ---- phase 1: label decode (wave 0 only; all 64 lanes stay for ballot)
    if (threadIdx.x < 64) {
        const int k = threadIdx.x;
        int has = 0;
        float cls = 0.f, tx = 0.f, ty = 0.f, tw = 0.f, th = 0.f;
        if (k < KL) {
            const float* L = labels + ((size_t)b * KL + k) * 5;
            cls = L[0];
            tw = L[3]; th = L[4];
            has = ((cls + L[1] + L[2] + tw + th) > 0.0f) ? 1 : 0;
            tx = L[1] * (float)NG;
            ty = L[2] * (float)NG;
        }
        unsigned long long bal = __ballot(has);
        int nlabel = __popcll(bal);

        if (k < KL) {
            int valid_k = (k < nlabel) ? 1 : 0;

            // anchor argmax: centered boxes -> overlap = min(w)*min(h).
            // keep exact division: argmax is selection-sensitive.
            float best = -1.0f; int bestn = 0;
            float area_t = tw * th;
            for (int n = 0; n < 9; ++n) {
                float aw = anchors_all[2 * n + 0] * inv_img;
                float ah = anchors_all[2 * n + 1] * inv_img;
                float inter = fmaxf(fminf(tw, aw), 0.0f) * fmaxf(fminf(th, ah), 0.0f);
                float iou = inter / fmaxf(area_t + aw * ah - inter, 1e-16f);
                if (iou > best) { best = iou; bestn = n; }  // first max wins
            }
            int va = 0;
            for (int t = 0; t < 3; ++t) va |= (bestn == anchor_indices[t]) ? 1 : 0;
            int bn = bestn % NA;
            int ti = (int)tx, tj = (int)ty;
            int valid = valid_k && va && (ti >= 0) && (ti < NG) && (tj >= 0) && (tj < NG);
            s_meta[k] = valid ? (bn * GG + tj * NG + ti) : -1;

            float vkf = valid_k ? 1.0f : 0.0f;
            float gx = tx * (1.0f / (float)NG) * vkf;
            float gy = ty * (1.0f / (float)NG) * vkf;
            float gw = tw * vkf, gh = th * vkf;
            s_box[k] = make_float4(gx - 0.5f * gw, gy - 0.5f * gh,
                                   gx + 0.5f * gw, gy + 0.5f * gh);
            s_c[k] = 0.375f * (gw * gh);   // 0.6/1.6 * areaB

            float naw = anchors_all[anchor_indices[bn] * 2 + 0] * inv_img;
            float nah = anchors_all[anchor_indices[bn] * 2 + 1] * inv_img;
            s_tgt[k][0] = tx - floorf(tx);
            s_tgt[k][1] = ty - floorf(ty);
            s_tgt[k][2] = __logf(tw / naw + 1e-16f);
            s_tgt[k][3] = __logf(th / nah + 1e-16f);
            s_w2[k] = 2.0f - tw * th;      // == tgt_scale^2 up to 1 ulp
            s_tc[k] = (int)cls;
        }
    }
    __syncthreads();

    // ---- phase 2: per-cell loss
    const int c0 = blockIdx.x * 256 + threadIdx.x;
    const bool live = c0 < CELLS;
    const int c = live ? c0 : 0;       // clamp: keep control flow uniform

    const int a = c / GG;
    const int r = c - a * GG;
    const int j = r / NG;
    const int i = r - j * NG;
    const float* R = raw + ((size_t)(b * NA + a) * NCH) * GG + r;

    float rx = R[0],      ry = R[GG];
    float rw = R[2 * GG], rh = R[3 * GG];
    float rc = R[4 * GG];

    float sx = __builtin_amdgcn_rcpf(1.0f + __expf(-rx));
    float sy = __builtin_amdgcn_rcpf(1.0f + __expf(-ry));

    int ai = anchor_indices[a];
    float aw = anchors_all[2 * ai + 0] * inv_img;
    float ah = anchors_all[2 * ai + 1] * inv_img;

    float px = (sx + (float)i) * (1.0f / (float)NG);
    float py = (sy + (float)j) * (1.0f / (float)NG);
    float pw = fminf(__expf(rw) * aw, 1.0f);
    float ph = fminf(__expf(rh) * ah, 1.0f);

    float tA = 0.375f * (pw * ph);     // 0.6/1.6 * areaA
    float ax0 = px - 0.5f * pw, ax1 = px + 0.5f * pw;
    float ay0 = py - 0.5f * ph, ay1 = py + 0.5f * ph;

    float margin = -1.0f;              // max_k (inter_k - 0.375*areaB_k)
    int kobj = -1;
    #pragma unroll 10
    for (int k = 0; k < KL; ++k) {
        float4 g = s_box[k];           // uniform-index LDS broadcast
        float iw = fminf(ax1, g.z) - fmaxf(ax0, g.x);
        float ih = fminf(ay1, g.w) - fmaxf(ay0, g.y);
        float inter = fmaxf(iw, 0.0f) * fmaxf(ih, 0.0f);
        margin = fmaxf(margin, inter - s_c[k]);
        kobj = (s_meta[k] == c) ? k : kobj;   // ascending k => last wins
    }
    bool ignore = margin > tA;         // iou>0.6 <=> inter>0.375(areaA+areaB)
    bool obj = (kobj >= 0) && live;

    float loss = 0.0f;
    // bce(sigmoid(z), t) == softplus(z) - t*z
    if (obj || !ignore)
        loss = softplusf(rc) - (obj ? rc : 0.0f);

    if (obj) {
        float w2 = s_w2[kobj];
        float t0 = s_tgt[kobj][0], t1 = s_tgt[kobj][1];
        float t2 = s_tgt[kobj][2], t3 = s_tgt[kobj][3];
        loss += w2 * ((softplusf(rx) - t0 * rx) + (softplusf(ry) - t1 * ry));
        float dw = rw - t2, dh = rh - t3;
        loss += 0.5f * w2 * (dw * dw + dh * dh);
        int tc = s_tc[kobj];
        float cl = 0.0f;
        #pragma unroll 8
        for (int cc = 0; cc < NCLS; ++cc) {
            float z = R[(5 + cc) * GG];
            cl += softplusf(z);
            if (cc == tc) cl -= z;
        }
        loss += cl;
    }
    if (!live) loss = 0.0f;

    // ---- phase 3: block reduction, one partial per block
    for (int off = 32; off > 0; off >>= 1)
        loss += __shfl_down(loss, off, 64);
    if ((threadIdx.x & 63) == 0) s_red[threadIdx.x >> 6] = loss;
    __syncthreads();
    if (threadIdx.x == 0)
        partials[(size_t)blockIdx.y * gridDim.x + blockIdx.x] =
            s_red[0] + s_red[1] + s_red[2] + s_red[3];
}

__global__ __launch_bounds__(256) void yolo_finalize(
    const float* __restrict__ partials, float* __restrict__ out)
{
    float s = 0.0f;
    for (int i = threadIdx.x; i < NPART; i += 256) s += partials[i];
    for (int off = 32; off > 0; off >>= 1)
        s += __shfl_down(s, off, 64);
    __shared__ float red[4];
    if ((threadIdx.x & 63) == 0) red[threadIdx.x >> 6] = s;
    __syncthreads();
    if (threadIdx.x == 0) out[0] = red[0] + red[1] + red[2] + red[3];
}

extern "C" void kernel_launch(void* const* d_in, const int* in_sizes, int n_in,
                              void* d_out, int out_size, void* d_ws, size_t ws_size,
                              hipStream_t stream) {
    const float* raw            = (const float*)d_in[0];
    const float* labels         = (const float*)d_in[1];
    const float* anchors_all    = (const float*)d_in[2];
    const int*   anchor_indices = (const int*)d_in[3];
    const int*   img_size_p     = (const int*)d_in[4];
    float* out = (float*)d_out;

    float* partials = (float*)d_ws;    // NPART floats

    dim3 grid(LOSS_BX, NB);
    yolo_fused<<<grid, 256, 0, stream>>>(raw, labels, anchors_all,
                                         anchor_indices, img_size_p, partials);
    yolo_finalize<<<1, 256, 0, stream>>>(partials, out);
}